// Round 6
// baseline (84.555 us; speedup 1.0000x reference)
//
#include <hip/hip_runtime.h>

#define HALFB 0.5f
#define CAPB  0.1f

__device__ __forceinline__ float clip05(float z) {
    return fminf(fmaxf(z, -HALFB), HALFB);   // v_med3_f32
}

// 4-lane xor-reduce via DPP quad_perm (pure VALU, no LDS pipe).
// 0xB1 = perm{1,0,3,2} (xor 1), 0x4E = perm{2,3,0,1} (xor 2).
template <int CTRL>
__device__ __forceinline__ float dppf(float v) {
    return __int_as_float(__builtin_amdgcn_update_dpp(
        __float_as_int(v), __float_as_int(v), CTRL, 0xF, 0xF, false));
}
__device__ __forceinline__ float red4f(float v) {
    v += dppf<0xB1>(v); v += dppf<0x4E>(v); return v;
}
__device__ __forceinline__ float min4f(float v) {
    v = fminf(v, dppf<0xB1>(v)); v = fminf(v, dppf<0x4E>(v)); return v;
}
__device__ __forceinline__ float max4f(float v) {
    v = fmaxf(v, dppf<0xB1>(v)); v = fmaxf(v, dppf<0x4E>(v)); return v;
}

// 4 lanes per row, 32 elems (8 x float4) per lane in VGPRs.
// Newton solver identical in semantics to rounds 2-5 (proven absmax 1.95e-3):
// safeguarded Newton on g(lam)=t, residual exit, exact final division.
__global__ __launch_bounds__(256, 8) void proj_kernel(
    const float* __restrict__ x, float* __restrict__ out, int nrows)
{
    const int lane = threadIdx.x & 63;
    const int wid  = (blockIdx.x << 2) | (threadIdx.x >> 6);
    const int q    = lane & 3;                     // quarter of row
    int row = (wid << 4) | (lane >> 2);            // 16 rows per wave
    if (row >= nrows) row = nrows - 1;             // grid divides exactly

    const float4* __restrict__ px = (const float4*)x  + ((size_t)row << 5) + (q << 3);
    float4*       __restrict__ po = (float4*)out      + ((size_t)row << 5) + (q << 3);

    float4 v[8];
    #pragma unroll
    for (int j = 0; j < 8; ++j) v[j] = px[j];

    // init sweep: 4-way partial trees for s0 / n_act / min / max
    float s0a = 0.f, s0b = 0.f, s0c = 0.f, s0d = 0.f;
    float naa = 0.f, nab = 0.f, nac = 0.f, nad = 0.f;
    float mna = 3.0e38f, mnb = 3.0e38f, mxa = -3.0e38f, mxb = -3.0e38f;
    #pragma unroll
    for (int j = 0; j < 8; ++j) {
        s0a += clip05(v[j].x); s0b += clip05(v[j].y);
        s0c += clip05(v[j].z); s0d += clip05(v[j].w);
        naa += (fabsf(v[j].x) < HALFB) ? 1.f : 0.f;
        nab += (fabsf(v[j].y) < HALFB) ? 1.f : 0.f;
        nac += (fabsf(v[j].z) < HALFB) ? 1.f : 0.f;
        nad += (fabsf(v[j].w) < HALFB) ? 1.f : 0.f;
        mna = fminf(mna, fminf(v[j].x, v[j].y));
        mnb = fminf(mnb, fminf(v[j].z, v[j].w));
        mxa = fmaxf(mxa, fmaxf(v[j].x, v[j].y));
        mxb = fmaxf(mxb, fmaxf(v[j].z, v[j].w));
    }
    float g  = red4f((s0a + s0b) + (s0c + s0d));
    float na = red4f((naa + nab) + (nac + nad));
    const float vmn = min4f(fminf(mna, mnb));
    const float vmx = max4f(fmaxf(mxa, mxb));

    const float t = fminf(fmaxf(g, -CAPB), CAPB);
    float lo  = vmn - (HALFB + CAPB);
    float hi  = vmx + (HALFB + CAPB);
    float lam = 0.f;

    for (int it = 0; it < 20; ++it) {
        if (fabsf(g - t) <= 1e-4f) break;     // final division heals residual
        if (g > t) lo = lam; else hi = lam;   // g decreasing in lam
        float ln;
        if (na > 0.f) {
            ln = lam + (g - t) * __builtin_amdgcn_rcpf(na);
            if (!(ln > lo && ln < hi)) ln = 0.5f * (lo + hi);
        } else {
            ln = 0.5f * (lo + hi);
        }
        if (ln == lam) break;
        lam = ln;

        float ga = 0.f, gb = 0.f, gc = 0.f, gd = 0.f;
        float pa = 0.f, pb = 0.f, pc = 0.f, pd = 0.f;
        #pragma unroll
        for (int j = 0; j < 8; ++j) {
            const float z0 = v[j].x - lam, z1 = v[j].y - lam;
            const float z2 = v[j].z - lam, z3 = v[j].w - lam;
            ga += clip05(z0); gb += clip05(z1);
            gc += clip05(z2); gd += clip05(z3);
            pa += (fabsf(z0) < HALFB) ? 1.f : 0.f;
            pb += (fabsf(z1) < HALFB) ? 1.f : 0.f;
            pc += (fabsf(z2) < HALFB) ? 1.f : 0.f;
            pd += (fabsf(z3) < HALFB) ? 1.f : 0.f;
        }
        g  = red4f((ga + gb) + (gc + gd));
        na = red4f((pa + pb) + (pc + pd));
    }

    // exact closed form over the active set (== reference's last step)
    const float lam_f = (na > 0.f) ? lam + (g - t) / na : lam;

    #pragma unroll
    for (int j = 0; j < 8; ++j) {
        po[j] = make_float4(clip05(v[j].x - lam_f), clip05(v[j].y - lam_f),
                            clip05(v[j].z - lam_f), clip05(v[j].w - lam_f));
    }
}

extern "C" void kernel_launch(void* const* d_in, const int* in_sizes, int n_in,
                              void* d_out, int out_size, void* d_ws, size_t ws_size,
                              hipStream_t stream) {
    const float* x = (const float*)d_in[0];
    float* out     = (float*)d_out;
    const int nrows = out_size / 128;             // 262144
    const int grid  = (nrows + 63) / 64;          // 4096 blocks, 64 rows each
    hipLaunchKernelGGL(proj_kernel, dim3(grid), dim3(256), 0, stream, x, out, nrows);
}

// Round 7
// 60.917 us; speedup vs baseline: 1.3881x; 1.3881x over previous
//
#include <hip/hip_runtime.h>

#define HALFB 0.5f
#define CAPB  0.1f

__device__ __forceinline__ float clip05(float z) {
    return fminf(fmaxf(z, -HALFB), HALFB);   // v_med3_f32
}

// 4-lane xor-reduce via DPP quad_perm (pure VALU, no LDS pipe).
// 0xB1 = perm{1,0,3,2} (xor 1), 0x4E = perm{2,3,0,1} (xor 2).
template <int CTRL>
__device__ __forceinline__ float dppf(float v) {
    return __int_as_float(__builtin_amdgcn_update_dpp(
        __float_as_int(v), __float_as_int(v), CTRL, 0xF, 0xF, false));
}
__device__ __forceinline__ float red4f(float v) {
    v += dppf<0xB1>(v); v += dppf<0x4E>(v); return v;
}
__device__ __forceinline__ float min4f(float v) {
    v = fminf(v, dppf<0xB1>(v)); v = fminf(v, dppf<0x4E>(v)); return v;
}
__device__ __forceinline__ float max4f(float v) {
    v = fmaxf(v, dppf<0xB1>(v)); v = fmaxf(v, dppf<0x4E>(v)); return v;
}

// 4 lanes per row, 32 elems (8 x float4) per lane in VGPRs.
// Newton solver identical in semantics to rounds 2-6 (proven absmax 1.95e-3).
// launch_bounds (256,4): VGPR cap 128 -> NO spills (round 6's (256,8) forced
// VGPR=32 and spilled the row buffer to scratch: +30MB HBM traffic, -27% perf).
__global__ __launch_bounds__(256, 4) void proj_kernel(
    const float* __restrict__ x, float* __restrict__ out, int nrows)
{
    const int lane = threadIdx.x & 63;
    const int wid  = (blockIdx.x << 2) | (threadIdx.x >> 6);
    const int q    = lane & 3;                     // quarter of row
    int row = (wid << 4) | (lane >> 2);            // 16 rows per wave
    if (row >= nrows) row = nrows - 1;             // grid divides exactly

    const float4* __restrict__ px = (const float4*)x  + ((size_t)row << 5) + (q << 3);
    float4*       __restrict__ po = (float4*)out      + ((size_t)row << 5) + (q << 3);

    float4 v[8];
    #pragma unroll
    for (int j = 0; j < 8; ++j) v[j] = px[j];

    // init sweep: 4-way partial trees for s0 / n_act / min / max
    float s0a = 0.f, s0b = 0.f, s0c = 0.f, s0d = 0.f;
    float naa = 0.f, nab = 0.f, nac = 0.f, nad = 0.f;
    float mna = 3.0e38f, mnb = 3.0e38f, mxa = -3.0e38f, mxb = -3.0e38f;
    #pragma unroll
    for (int j = 0; j < 8; ++j) {
        s0a += clip05(v[j].x); s0b += clip05(v[j].y);
        s0c += clip05(v[j].z); s0d += clip05(v[j].w);
        naa += (fabsf(v[j].x) < HALFB) ? 1.f : 0.f;
        nab += (fabsf(v[j].y) < HALFB) ? 1.f : 0.f;
        nac += (fabsf(v[j].z) < HALFB) ? 1.f : 0.f;
        nad += (fabsf(v[j].w) < HALFB) ? 1.f : 0.f;
        mna = fminf(mna, fminf(v[j].x, v[j].y));
        mnb = fminf(mnb, fminf(v[j].z, v[j].w));
        mxa = fmaxf(mxa, fmaxf(v[j].x, v[j].y));
        mxb = fmaxf(mxb, fmaxf(v[j].z, v[j].w));
    }
    float g  = red4f((s0a + s0b) + (s0c + s0d));
    float na = red4f((naa + nab) + (nac + nad));
    const float vmn = min4f(fminf(mna, mnb));
    const float vmx = max4f(fmaxf(mxa, mxb));

    const float t = fminf(fmaxf(g, -CAPB), CAPB);
    float lo  = vmn - (HALFB + CAPB);
    float hi  = vmx + (HALFB + CAPB);
    float lam = 0.f;

    for (int it = 0; it < 20; ++it) {
        if (fabsf(g - t) <= 1e-4f) break;     // final division heals residual
        if (g > t) lo = lam; else hi = lam;   // g decreasing in lam
        float ln;
        if (na > 0.f) {
            ln = lam + (g - t) * __builtin_amdgcn_rcpf(na);
            if (!(ln > lo && ln < hi)) ln = 0.5f * (lo + hi);
        } else {
            ln = 0.5f * (lo + hi);
        }
        if (ln == lam) break;
        lam = ln;

        float ga = 0.f, gb = 0.f, gc = 0.f, gd = 0.f;
        float pa = 0.f, pb = 0.f, pc = 0.f, pd = 0.f;
        #pragma unroll
        for (int j = 0; j < 8; ++j) {
            const float z0 = v[j].x - lam, z1 = v[j].y - lam;
            const float z2 = v[j].z - lam, z3 = v[j].w - lam;
            ga += clip05(z0); gb += clip05(z1);
            gc += clip05(z2); gd += clip05(z3);
            pa += (fabsf(z0) < HALFB) ? 1.f : 0.f;
            pb += (fabsf(z1) < HALFB) ? 1.f : 0.f;
            pc += (fabsf(z2) < HALFB) ? 1.f : 0.f;
            pd += (fabsf(z3) < HALFB) ? 1.f : 0.f;
        }
        g  = red4f((ga + gb) + (gc + gd));
        na = red4f((pa + pb) + (pc + pd));
    }

    // exact closed form over the active set (== reference's last step)
    const float lam_f = (na > 0.f) ? lam + (g - t) / na : lam;

    #pragma unroll
    for (int j = 0; j < 8; ++j) {
        po[j] = make_float4(clip05(v[j].x - lam_f), clip05(v[j].y - lam_f),
                            clip05(v[j].z - lam_f), clip05(v[j].w - lam_f));
    }
}

extern "C" void kernel_launch(void* const* d_in, const int* in_sizes, int n_in,
                              void* d_out, int out_size, void* d_ws, size_t ws_size,
                              hipStream_t stream) {
    const float* x = (const float*)d_in[0];
    float* out     = (float*)d_out;
    const int nrows = out_size / 128;             // 262144
    const int grid  = (nrows + 63) / 64;          // 4096 blocks, 64 rows each
    hipLaunchKernelGGL(proj_kernel, dim3(grid), dim3(256), 0, stream, x, out, nrows);
}

// Round 8
// 46.769 us; speedup vs baseline: 1.8080x; 1.3025x over previous
//
#include <hip/hip_runtime.h>

#define HALFB 0.5f
#define CAPB  0.1f

__device__ __forceinline__ float clip05(float z) {
    return fminf(fmaxf(z, -HALFB), HALFB);   // v_med3_f32
}

// 4-lane xor-reduce via DPP quad_perm (pure VALU, no LDS pipe).
template <int CTRL>
__device__ __forceinline__ float dppf(float v) {
    return __int_as_float(__builtin_amdgcn_update_dpp(
        __float_as_int(v), __float_as_int(v), CTRL, 0xF, 0xF, false));
}
__device__ __forceinline__ float red4f(float v) {
    v += dppf<0xB1>(v); v += dppf<0x4E>(v); return v;
}
__device__ __forceinline__ float min4f(float v) {
    v = fminf(v, dppf<0xB1>(v)); v = fminf(v, dppf<0x4E>(v)); return v;
}
__device__ __forceinline__ float max4f(float v) {
    v = fmaxf(v, dppf<0xB1>(v)); v = fmaxf(v, dppf<0x4E>(v)); return v;
}

// 4 lanes per row; INTERLEAVED ownership: lane q owns float4s {q, q+4, ..., q+28}
// of its row. Per memory instruction the 4-lane group covers one dense 64B line
// (16 lines/wave-instr instead of 64 -> 4x less TA/L1-tag work). The solve is
// elementwise-symmetric, so ownership permutation doesn't change the math.
__global__ __launch_bounds__(256, 4) void proj_kernel(
    const float* __restrict__ x, float* __restrict__ out, int nrows)
{
    const int lane = threadIdx.x & 63;
    const int wid  = (blockIdx.x << 2) | (threadIdx.x >> 6);
    const int q    = lane & 3;
    int row = (wid << 4) | (lane >> 2);            // 16 rows per wave
    if (row >= nrows) row = nrows - 1;             // grid divides exactly

    const float4* __restrict__ px = (const float4*)x  + ((size_t)row << 5) + q;
    float4*       __restrict__ po = (float4*)out      + ((size_t)row << 5) + q;

    float4 v[8];
    #pragma unroll
    for (int j = 0; j < 8; ++j) v[j] = px[j << 2];   // stride 4 float4s = 64B

    // init sweep: 4-way partial trees for s0 / n_act / min / max
    float s0a = 0.f, s0b = 0.f, s0c = 0.f, s0d = 0.f;
    float naa = 0.f, nab = 0.f, nac = 0.f, nad = 0.f;
    float mna = 3.0e38f, mnb = 3.0e38f, mxa = -3.0e38f, mxb = -3.0e38f;
    #pragma unroll
    for (int j = 0; j < 8; ++j) {
        s0a += clip05(v[j].x); s0b += clip05(v[j].y);
        s0c += clip05(v[j].z); s0d += clip05(v[j].w);
        naa += (fabsf(v[j].x) < HALFB) ? 1.f : 0.f;
        nab += (fabsf(v[j].y) < HALFB) ? 1.f : 0.f;
        nac += (fabsf(v[j].z) < HALFB) ? 1.f : 0.f;
        nad += (fabsf(v[j].w) < HALFB) ? 1.f : 0.f;
        mna = fminf(mna, fminf(v[j].x, v[j].y));
        mnb = fminf(mnb, fminf(v[j].z, v[j].w));
        mxa = fmaxf(mxa, fmaxf(v[j].x, v[j].y));
        mxb = fmaxf(mxb, fmaxf(v[j].z, v[j].w));
    }
    float g  = red4f((s0a + s0b) + (s0c + s0d));
    float na = red4f((naa + nab) + (nac + nad));
    const float vmn = min4f(fminf(mna, mnb));
    const float vmx = max4f(fmaxf(mxa, mxb));

    const float t = fminf(fmaxf(g, -CAPB), CAPB);
    float lo  = vmn - (HALFB + CAPB);
    float hi  = vmx + (HALFB + CAPB);
    float lam = 0.f;

    for (int it = 0; it < 20; ++it) {
        if (fabsf(g - t) <= 1e-4f) break;     // final division heals residual
        if (g > t) lo = lam; else hi = lam;   // g decreasing in lam
        float ln;
        if (na > 0.f) {
            ln = lam + (g - t) * __builtin_amdgcn_rcpf(na);
            if (!(ln > lo && ln < hi)) ln = 0.5f * (lo + hi);
        } else {
            ln = 0.5f * (lo + hi);
        }
        if (ln == lam) break;
        lam = ln;

        float ga = 0.f, gb = 0.f, gc = 0.f, gd = 0.f;
        float pa = 0.f, pb = 0.f, pc = 0.f, pd = 0.f;
        #pragma unroll
        for (int j = 0; j < 8; ++j) {
            const float z0 = v[j].x - lam, z1 = v[j].y - lam;
            const float z2 = v[j].z - lam, z3 = v[j].w - lam;
            ga += clip05(z0); gb += clip05(z1);
            gc += clip05(z2); gd += clip05(z3);
            pa += (fabsf(z0) < HALFB) ? 1.f : 0.f;
            pb += (fabsf(z1) < HALFB) ? 1.f : 0.f;
            pc += (fabsf(z2) < HALFB) ? 1.f : 0.f;
            pd += (fabsf(z3) < HALFB) ? 1.f : 0.f;
        }
        g  = red4f((ga + gb) + (gc + gd));
        na = red4f((pa + pb) + (pc + pd));
    }

    // exact closed form over the active set (== reference's last step)
    const float lam_f = (na > 0.f) ? lam + (g - t) / na : lam;

    #pragma unroll
    for (int j = 0; j < 8; ++j) {
        po[j << 2] = make_float4(clip05(v[j].x - lam_f), clip05(v[j].y - lam_f),
                                 clip05(v[j].z - lam_f), clip05(v[j].w - lam_f));
    }
}

extern "C" void kernel_launch(void* const* d_in, const int* in_sizes, int n_in,
                              void* d_out, int out_size, void* d_ws, size_t ws_size,
                              hipStream_t stream) {
    const float* x = (const float*)d_in[0];
    float* out     = (float*)d_out;
    const int nrows = out_size / 128;             // 262144
    const int grid  = (nrows + 63) / 64;          // 4096 blocks, 64 rows each
    hipLaunchKernelGGL(proj_kernel, dim3(grid), dim3(256), 0, stream, x, out, nrows);
}